// Round 1
// baseline (1303.442 us; speedup 1.0000x reference)
//
#include <hip/hip_runtime.h>

#define NP 200000
#define NA 100000
#define NE 1200000

// ---------------- CSR build ----------------

__global__ __launch_bounds__(256) void hist_k(const int* __restrict__ row, int* __restrict__ cnt, int n) {
    int i = blockIdx.x * blockDim.x + threadIdx.x;
    int stride = gridDim.x * blockDim.x;
    for (; i < n; i += stride) atomicAdd(&cnt[row[i]], 1);
}

// exclusive scan, 1024 elements/block (256 thr x 4), partial per block + block sums
__global__ __launch_bounds__(256) void scan1_k(const int* __restrict__ in, int* __restrict__ out,
                                               int* __restrict__ bsums, int n) {
    __shared__ int lds[256];
    int t = threadIdx.x;
    int base = blockIdx.x * 1024 + t * 4;
    int v0 = (base + 0 < n) ? in[base + 0] : 0;
    int v1 = (base + 1 < n) ? in[base + 1] : 0;
    int v2 = (base + 2 < n) ? in[base + 2] : 0;
    int v3 = (base + 3 < n) ? in[base + 3] : 0;
    lds[t] = v0 + v1 + v2 + v3;
    __syncthreads();
    for (int off = 1; off < 256; off <<= 1) {
        int x = (t >= off) ? lds[t - off] : 0;
        __syncthreads();
        lds[t] += x;
        __syncthreads();
    }
    if (t == 255) bsums[blockIdx.x] = lds[255];
    int run = (t == 0) ? 0 : lds[t - 1];
    if (base + 0 < n) out[base + 0] = run; run += v0;
    if (base + 1 < n) out[base + 1] = run; run += v1;
    if (base + 2 < n) out[base + 2] = run; run += v2;
    if (base + 3 < n) out[base + 3] = run;
}

__global__ void scan2_k(int* bsums, int nb) {  // nb <= 256, single block
    __shared__ int lds[256];
    int t = threadIdx.x;
    int v = (t < nb) ? bsums[t] : 0;
    lds[t] = v;
    __syncthreads();
    for (int off = 1; off < 256; off <<= 1) {
        int x = (t >= off) ? lds[t - off] : 0;
        __syncthreads();
        lds[t] += x;
        __syncthreads();
    }
    if (t < nb) bsums[t] = (t == 0) ? 0 : lds[t - 1];
}

__global__ __launch_bounds__(256) void scan3_k(int* __restrict__ out, const int* __restrict__ bsums, int n) {
    int add = bsums[blockIdx.x];
    int base = blockIdx.x * 1024 + threadIdx.x * 4;
#pragma unroll
    for (int j = 0; j < 4; j++)
        if (base + j < n) out[base + j] += add;
}

__global__ __launch_bounds__(256) void scatter_k(const int* __restrict__ row, const int* __restrict__ col,
                                                 const float* __restrict__ val, const int* __restrict__ off,
                                                 int* __restrict__ cursor, int2* __restrict__ csr, int n) {
    int i = blockIdx.x * blockDim.x + threadIdx.x;
    int stride = gridDim.x * blockDim.x;
    for (; i < n; i += stride) {
        int r = row[i];
        int pos = off[r] + atomicAdd(&cursor[r], 1);
        csr[pos] = make_int2(col[i], __float_as_int(val[i]));
    }
}

// ---------------- SpMM gather: 16 lanes per output row, float4/lane ----------------

__global__ __launch_bounds__(256) void spmm_k(const int2* __restrict__ csr, const int* __restrict__ off,
                                              const int* __restrict__ cnt, const float4* __restrict__ z,
                                              float4* __restrict__ out, int nrows) {
    int g = blockIdx.x * 16 + (threadIdx.x >> 4);
    int l = threadIdx.x & 15;
    if (g >= nrows) return;
    int start = off[g], deg = cnt[g];
    float4 acc = make_float4(0.f, 0.f, 0.f, 0.f);
    for (int j = 0; j < deg; j++) {
        int2 e = csr[start + j];          // broadcast across the 16-lane group
        float v = __int_as_float(e.y);
        float4 zz = z[(size_t)e.x * 16 + l];
        acc.x += v * zz.x;
        acc.y += v * zz.y;
        acc.z += v * zz.z;
        acc.w += v * zz.w;
    }
    out[(size_t)g * 16 + l] = acc;
}

// ---------------- dense projection: z = x @ W, D=64; wave per 4 rows ----------------

template <int K>
__global__ __launch_bounds__(256) void gemm64_k(const float* __restrict__ x, const float* __restrict__ w,
                                                float* __restrict__ z, int nrows) {
    __shared__ float wl[K * 64];
    for (int i = threadIdx.x * 4; i < K * 64; i += 1024)
        *(float4*)&wl[i] = *(const float4*)&w[i];
    __syncthreads();
    int wave = threadIdx.x >> 6, lane = threadIdx.x & 63;
    int row0 = blockIdx.x * 16 + wave * 4;
    row0 = __builtin_amdgcn_readfirstlane(row0);  // force scalar address path for x loads
    if (row0 >= nrows) return;
    const float* x0 = x + (size_t)row0 * K;
    float acc0 = 0.f, acc1 = 0.f, acc2 = 0.f, acc3 = 0.f;
#pragma unroll 4
    for (int k4 = 0; k4 < K / 4; k4++) {
        int k = 4 * k4;
        float w0 = wl[(k + 0) * 64 + lane];
        float w1 = wl[(k + 1) * 64 + lane];
        float w2 = wl[(k + 2) * 64 + lane];
        float w3 = wl[(k + 3) * 64 + lane];
        float4 a = *(const float4*)&x0[0 * K + k];
        float4 b = *(const float4*)&x0[1 * K + k];
        float4 c = *(const float4*)&x0[2 * K + k];
        float4 d = *(const float4*)&x0[3 * K + k];
        acc0 += a.x * w0 + a.y * w1 + a.z * w2 + a.w * w3;
        acc1 += b.x * w0 + b.y * w1 + b.z * w2 + b.w * w3;
        acc2 += c.x * w0 + c.y * w1 + c.z * w2 + c.w * w3;
        acc3 += d.x * w0 + d.y * w1 + d.z * w2 + d.w * w3;
    }
    z[(size_t)(row0 + 0) * 64 + lane] = acc0;
    z[(size_t)(row0 + 1) * 64 + lane] = acc1;
    z[(size_t)(row0 + 2) * 64 + lane] = acc2;
    z[(size_t)(row0 + 3) * 64 + lane] = acc3;
}

// ---------------- launch ----------------

extern "C" void kernel_launch(void* const* d_in, const int* in_sizes, int n_in,
                              void* d_out, int out_size, void* d_ws, size_t ws_size,
                              hipStream_t stream) {
    const float* x_paper  = (const float*)d_in[0];
    const float* x_author = (const float*)d_in[1];
    const float* W_paper  = (const float*)d_in[2];
    const float* W_author = (const float*)d_in[3];
    const int*   pa_row   = (const int*)d_in[4];
    const int*   pa_col   = (const int*)d_in[5];
    const float* pa_val   = (const float*)d_in[6];
    const int*   ap_row   = (const int*)d_in[7];
    const int*   ap_col   = (const int*)d_in[8];
    const float* ap_val   = (const float*)d_in[9];

    char* ws = (char*)d_ws;
    size_t o = 0;
    auto alloc = [&](size_t bytes) -> char* {
        char* p = ws + o;
        o += (bytes + 255) & ~(size_t)255;
        return p;
    };
    float* zp     = (float*)alloc((size_t)NP * 64 * 4);  // also reused for g
    float* za     = (float*)alloc((size_t)NA * 64 * 4);
    float* h      = (float*)alloc((size_t)NA * 64 * 4);  // also reused for h2
    int2*  csr_pa = (int2*)alloc((size_t)NE * 8);
    int2*  csr_ap = (int2*)alloc((size_t)NE * 8);
    int* cnt_pa = (int*)alloc(NA * 4);
    int* off_pa = (int*)alloc(NA * 4);
    int* cnt_ap = (int*)alloc(NP * 4);
    int* off_ap = (int*)alloc(NP * 4);
    int* cursor = (int*)alloc(NP * 4);
    int* bsums  = (int*)alloc(1024 * 4);

    float* out_pap   = (float*)d_out;
    float* out_papap = out_pap + (size_t)NP * 64;
    float* out_apa   = out_papap + (size_t)NP * 64;

    const int nb_a = (NA + 1023) / 1024;  // 98
    const int nb_p = (NP + 1023) / 1024;  // 196

    // CSR build: pa (rows = authors), ap (rows = papers)
    hipMemsetAsync(cnt_pa, 0, NA * 4, stream);
    hipMemsetAsync(cnt_ap, 0, NP * 4, stream);
    hist_k<<<1024, 256, 0, stream>>>(pa_row, cnt_pa, NE);
    hist_k<<<1024, 256, 0, stream>>>(ap_row, cnt_ap, NE);

    scan1_k<<<nb_a, 256, 0, stream>>>(cnt_pa, off_pa, bsums, NA);
    scan2_k<<<1, 256, 0, stream>>>(bsums, nb_a);
    scan3_k<<<nb_a, 256, 0, stream>>>(off_pa, bsums, NA);
    hipMemsetAsync(cursor, 0, NA * 4, stream);
    scatter_k<<<1024, 256, 0, stream>>>(pa_row, pa_col, pa_val, off_pa, cursor, csr_pa, NE);

    scan1_k<<<nb_p, 256, 0, stream>>>(cnt_ap, off_ap, bsums, NP);
    scan2_k<<<1, 256, 0, stream>>>(bsums, nb_p);
    scan3_k<<<nb_p, 256, 0, stream>>>(off_ap, bsums, NP);
    hipMemsetAsync(cursor, 0, NP * 4, stream);
    scatter_k<<<1024, 256, 0, stream>>>(ap_row, ap_col, ap_val, off_ap, cursor, csr_ap, NE);

    // projections
    gemm64_k<256><<<NP / 16, 256, 0, stream>>>(x_paper, W_paper, zp, NP);
    gemm64_k<128><<<NA / 16, 256, 0, stream>>>(x_author, W_author, za, NA);

    // P-A-P: h = pa@zp ; pap = ap@h
    spmm_k<<<NA / 16, 256, 0, stream>>>(csr_pa, off_pa, cnt_pa, (const float4*)zp, (float4*)h, NA);
    spmm_k<<<NP / 16, 256, 0, stream>>>(csr_ap, off_ap, cnt_ap, (const float4*)h, (float4*)out_pap, NP);
    // P-A-P-A-P: h2 = pa@pap (reuse h) ; papap = ap@h2
    spmm_k<<<NA / 16, 256, 0, stream>>>(csr_pa, off_pa, cnt_pa, (const float4*)out_pap, (float4*)h, NA);
    spmm_k<<<NP / 16, 256, 0, stream>>>(csr_ap, off_ap, cnt_ap, (const float4*)h, (float4*)out_papap, NP);
    // A-P-A: g = ap@za (reuse zp) ; apa = pa@g
    spmm_k<<<NP / 16, 256, 0, stream>>>(csr_ap, off_ap, cnt_ap, (const float4*)za, (float4*)zp, NP);
    spmm_k<<<NA / 16, 256, 0, stream>>>(csr_pa, off_pa, cnt_pa, (const float4*)zp, (float4*)out_apa, NA);
}

// Round 2
// 953.164 us; speedup vs baseline: 1.3675x; 1.3675x over previous
//
#include <hip/hip_runtime.h>

#define NP 200000
#define NA 100000
#define NE 1200000

// ---------------- CSR build ----------------

__global__ __launch_bounds__(256) void hist_k(const int* __restrict__ row, int* __restrict__ cnt, int n) {
    int i = blockIdx.x * blockDim.x + threadIdx.x;
    int stride = gridDim.x * blockDim.x;
    for (; i < n; i += stride) atomicAdd(&cnt[row[i]], 1);
}

// exclusive scan, 1024 elements/block (256 thr x 4), partial per block + block sums
__global__ __launch_bounds__(256) void scan1_k(const int* __restrict__ in, int* __restrict__ out,
                                               int* __restrict__ bsums, int n) {
    __shared__ int lds[256];
    int t = threadIdx.x;
    int base = blockIdx.x * 1024 + t * 4;
    int v0 = (base + 0 < n) ? in[base + 0] : 0;
    int v1 = (base + 1 < n) ? in[base + 1] : 0;
    int v2 = (base + 2 < n) ? in[base + 2] : 0;
    int v3 = (base + 3 < n) ? in[base + 3] : 0;
    lds[t] = v0 + v1 + v2 + v3;
    __syncthreads();
    for (int off = 1; off < 256; off <<= 1) {
        int x = (t >= off) ? lds[t - off] : 0;
        __syncthreads();
        lds[t] += x;
        __syncthreads();
    }
    if (t == 255) bsums[blockIdx.x] = lds[255];
    int run = (t == 0) ? 0 : lds[t - 1];
    if (base + 0 < n) out[base + 0] = run; run += v0;
    if (base + 1 < n) out[base + 1] = run; run += v1;
    if (base + 2 < n) out[base + 2] = run; run += v2;
    if (base + 3 < n) out[base + 3] = run;
}

__global__ void scan2_k(int* bsums, int nb) {  // nb <= 256, single block
    __shared__ int lds[256];
    int t = threadIdx.x;
    int v = (t < nb) ? bsums[t] : 0;
    lds[t] = v;
    __syncthreads();
    for (int off = 1; off < 256; off <<= 1) {
        int x = (t >= off) ? lds[t - off] : 0;
        __syncthreads();
        lds[t] += x;
        __syncthreads();
    }
    if (t < nb) bsums[t] = (t == 0) ? 0 : lds[t - 1];
}

__global__ __launch_bounds__(256) void scan3_k(int* __restrict__ out, const int* __restrict__ bsums, int n) {
    int add = bsums[blockIdx.x];
    int base = blockIdx.x * 1024 + threadIdx.x * 4;
#pragma unroll
    for (int j = 0; j < 4; j++)
        if (base + j < n) out[base + j] += add;
}

__global__ __launch_bounds__(256) void scatter_k(const int* __restrict__ row, const int* __restrict__ col,
                                                 const float* __restrict__ val, const int* __restrict__ off,
                                                 int* __restrict__ cursor, int2* __restrict__ csr, int n) {
    int i = blockIdx.x * blockDim.x + threadIdx.x;
    int stride = gridDim.x * blockDim.x;
    for (; i < n; i += stride) {
        int r = row[i];
        int pos = off[r] + atomicAdd(&cursor[r], 1);
        csr[pos] = make_int2(col[i], __float_as_int(val[i]));
    }
}

// ---------------- SpMM gather: 16 lanes per output row, float4/lane, edge-unroll 4 ----------------

__global__ __launch_bounds__(256) void spmm_k(const int2* __restrict__ csr, const int* __restrict__ off,
                                              const int* __restrict__ cnt, const float4* __restrict__ z,
                                              float4* __restrict__ out, int nrows) {
    int g = blockIdx.x * 16 + (threadIdx.x >> 4);
    int l = threadIdx.x & 15;
    if (g >= nrows) return;
    int start = off[g], deg = cnt[g];
    float4 acc = make_float4(0.f, 0.f, 0.f, 0.f);
    if (deg > 0) {
        for (int j = 0; j < deg; j += 4) {
            int j1 = min(j + 1, deg - 1);
            int j2 = min(j + 2, deg - 1);
            int j3 = min(j + 3, deg - 1);
            int2 e0 = csr[start + j];
            int2 e1 = csr[start + j1];
            int2 e2 = csr[start + j2];
            int2 e3 = csr[start + j3];
            float4 z0 = z[(size_t)e0.x * 16 + l];
            float4 z1 = z[(size_t)e1.x * 16 + l];
            float4 z2 = z[(size_t)e2.x * 16 + l];
            float4 z3 = z[(size_t)e3.x * 16 + l];
            float v0 = __int_as_float(e0.y);
            float v1 = (j + 1 < deg) ? __int_as_float(e1.y) : 0.f;
            float v2 = (j + 2 < deg) ? __int_as_float(e2.y) : 0.f;
            float v3 = (j + 3 < deg) ? __int_as_float(e3.y) : 0.f;
            acc.x += v0 * z0.x + v1 * z1.x + v2 * z2.x + v3 * z3.x;
            acc.y += v0 * z0.y + v1 * z1.y + v2 * z2.y + v3 * z3.y;
            acc.z += v0 * z0.z + v1 * z1.z + v2 * z2.z + v3 * z3.z;
            acc.w += v0 * z0.w + v1 * z1.w + v2 * z2.w + v3 * z3.w;
        }
    }
    out[(size_t)g * 16 + l] = acc;
}

// ---------------- dense projection: z = x @ W, D=64 ----------------
// block = 256 threads computes 256 rows x 64 cols; K-tile 32 staged in LDS
// (x transposed 32KB + W 8KB = 40KB -> 4 blocks/CU); 8x8 per-thread register tile.

template <int K>
__global__ __launch_bounds__(256) void gemm64_k(const float* __restrict__ x, const float* __restrict__ w,
                                                float* __restrict__ z, int nrows) {
    __shared__ float xs[32][256];  // [kk][row_local]
    __shared__ float wsh[32][64];  // [kk][col]
    int t = threadIdx.x;
    int tx = t & 7;    // col group: cols tx*8 .. tx*8+7
    int ty = t >> 3;   // row group: rows ty*8 .. ty*8+7
    int r0 = blockIdx.x * 256;

    float acc[8][8];
#pragma unroll
    for (int i = 0; i < 8; i++)
#pragma unroll
        for (int j = 0; j < 8; j++) acc[i][j] = 0.f;

    for (int k0 = 0; k0 < K; k0 += 32) {
        __syncthreads();  // previous tile fully consumed
        // stage x tile: this thread owns global row r0+t, k in [k0, k0+32)
        {
            int row = r0 + t;
            float4 f[8];
            if (row < nrows) {
                const float* xp = x + (size_t)row * K + k0;
#pragma unroll
                for (int q = 0; q < 8; q++) f[q] = *(const float4*)&xp[q * 4];
            } else {
#pragma unroll
                for (int q = 0; q < 8; q++) f[q] = make_float4(0.f, 0.f, 0.f, 0.f);
            }
#pragma unroll
            for (int q = 0; q < 8; q++) {
                xs[q * 4 + 0][t] = f[q].x;
                xs[q * 4 + 1][t] = f[q].y;
                xs[q * 4 + 2][t] = f[q].z;
                xs[q * 4 + 3][t] = f[q].w;
            }
            // stage W tile: 32x64 contiguous floats, 8 per thread
            const float* wp = w + (size_t)k0 * 64;
            float* wflat = &wsh[0][0];
            *(float4*)&wflat[t * 8 + 0] = *(const float4*)&wp[t * 8 + 0];
            *(float4*)&wflat[t * 8 + 4] = *(const float4*)&wp[t * 8 + 4];
        }
        __syncthreads();
#pragma unroll 8
        for (int kk = 0; kk < 32; kk++) {
            float a[8], b[8];
            *(float4*)&a[0] = *(float4*)&xs[kk][ty * 8 + 0];
            *(float4*)&a[4] = *(float4*)&xs[kk][ty * 8 + 4];
            *(float4*)&b[0] = *(float4*)&wsh[kk][tx * 8 + 0];
            *(float4*)&b[4] = *(float4*)&wsh[kk][tx * 8 + 4];
#pragma unroll
            for (int i = 0; i < 8; i++)
#pragma unroll
                for (int j = 0; j < 8; j++) acc[i][j] = fmaf(a[i], b[j], acc[i][j]);
        }
    }

    int row0 = r0 + ty * 8;
    if (row0 < nrows) {  // nrows % 8 == 0, so all 8 rows valid together
#pragma unroll
        for (int i = 0; i < 8; i++) {
            float* zp = z + (size_t)(row0 + i) * 64 + tx * 8;
            *(float4*)&zp[0] = make_float4(acc[i][0], acc[i][1], acc[i][2], acc[i][3]);
            *(float4*)&zp[4] = make_float4(acc[i][4], acc[i][5], acc[i][6], acc[i][7]);
        }
    }
}

// ---------------- launch ----------------

extern "C" void kernel_launch(void* const* d_in, const int* in_sizes, int n_in,
                              void* d_out, int out_size, void* d_ws, size_t ws_size,
                              hipStream_t stream) {
    const float* x_paper  = (const float*)d_in[0];
    const float* x_author = (const float*)d_in[1];
    const float* W_paper  = (const float*)d_in[2];
    const float* W_author = (const float*)d_in[3];
    const int*   pa_row   = (const int*)d_in[4];
    const int*   pa_col   = (const int*)d_in[5];
    const float* pa_val   = (const float*)d_in[6];
    const int*   ap_row   = (const int*)d_in[7];
    const int*   ap_col   = (const int*)d_in[8];
    const float* ap_val   = (const float*)d_in[9];

    char* ws = (char*)d_ws;
    size_t o = 0;
    auto alloc = [&](size_t bytes) -> char* {
        char* p = ws + o;
        o += (bytes + 255) & ~(size_t)255;
        return p;
    };
    float* zp     = (float*)alloc((size_t)NP * 64 * 4);  // also reused for g
    float* za     = (float*)alloc((size_t)NA * 64 * 4);
    float* h      = (float*)alloc((size_t)NA * 64 * 4);  // also reused for h2
    int2*  csr_pa = (int2*)alloc((size_t)NE * 8);
    int2*  csr_ap = (int2*)alloc((size_t)NE * 8);
    int* cnt_pa = (int*)alloc(NA * 4);
    int* off_pa = (int*)alloc(NA * 4);
    int* cnt_ap = (int*)alloc(NP * 4);
    int* off_ap = (int*)alloc(NP * 4);
    int* cursor = (int*)alloc(NP * 4);
    int* bsums  = (int*)alloc(1024 * 4);

    float* out_pap   = (float*)d_out;
    float* out_papap = out_pap + (size_t)NP * 64;
    float* out_apa   = out_papap + (size_t)NP * 64;

    const int nb_a = (NA + 1023) / 1024;  // 98
    const int nb_p = (NP + 1023) / 1024;  // 196

    // CSR build: pa (rows = authors), ap (rows = papers)
    hipMemsetAsync(cnt_pa, 0, NA * 4, stream);
    hipMemsetAsync(cnt_ap, 0, NP * 4, stream);
    hist_k<<<1024, 256, 0, stream>>>(pa_row, cnt_pa, NE);
    hist_k<<<1024, 256, 0, stream>>>(ap_row, cnt_ap, NE);

    scan1_k<<<nb_a, 256, 0, stream>>>(cnt_pa, off_pa, bsums, NA);
    scan2_k<<<1, 256, 0, stream>>>(bsums, nb_a);
    scan3_k<<<nb_a, 256, 0, stream>>>(off_pa, bsums, NA);
    hipMemsetAsync(cursor, 0, NA * 4, stream);
    scatter_k<<<1024, 256, 0, stream>>>(pa_row, pa_col, pa_val, off_pa, cursor, csr_pa, NE);

    scan1_k<<<nb_p, 256, 0, stream>>>(cnt_ap, off_ap, bsums, NP);
    scan2_k<<<1, 256, 0, stream>>>(bsums, nb_p);
    scan3_k<<<nb_p, 256, 0, stream>>>(off_ap, bsums, NP);
    hipMemsetAsync(cursor, 0, NP * 4, stream);
    scatter_k<<<1024, 256, 0, stream>>>(ap_row, ap_col, ap_val, off_ap, cursor, csr_ap, NE);

    // projections (register-tiled GEMM)
    gemm64_k<256><<<(NP + 255) / 256, 256, 0, stream>>>(x_paper, W_paper, zp, NP);
    gemm64_k<128><<<(NA + 255) / 256, 256, 0, stream>>>(x_author, W_author, za, NA);

    // P-A-P: h = pa@zp ; pap = ap@h
    spmm_k<<<NA / 16, 256, 0, stream>>>(csr_pa, off_pa, cnt_pa, (const float4*)zp, (float4*)h, NA);
    spmm_k<<<NP / 16, 256, 0, stream>>>(csr_ap, off_ap, cnt_ap, (const float4*)h, (float4*)out_pap, NP);
    // P-A-P-A-P: h2 = pa@pap (reuse h) ; papap = ap@h2
    spmm_k<<<NA / 16, 256, 0, stream>>>(csr_pa, off_pa, cnt_pa, (const float4*)out_pap, (float4*)h, NA);
    spmm_k<<<NP / 16, 256, 0, stream>>>(csr_ap, off_ap, cnt_ap, (const float4*)h, (float4*)out_papap, NP);
    // A-P-A: g = ap@za (reuse zp) ; apa = pa@g
    spmm_k<<<NP / 16, 256, 0, stream>>>(csr_ap, off_ap, cnt_ap, (const float4*)za, (float4*)zp, NP);
    spmm_k<<<NA / 16, 256, 0, stream>>>(csr_pa, off_pa, cnt_pa, (const float4*)zp, (float4*)out_apa, NA);
}

// Round 3
// 878.639 us; speedup vs baseline: 1.4835x; 1.0848x over previous
//
#include <hip/hip_runtime.h>
#include <hip/hip_fp16.h>

#define NP 200000
#define NA 100000
#define NE 1200000

// ---------------- CSR build ----------------

__global__ __launch_bounds__(256) void hist_k(const int* __restrict__ row, int* __restrict__ cnt, int n) {
    int i = blockIdx.x * blockDim.x + threadIdx.x;
    int stride = gridDim.x * blockDim.x;
    for (; i < n; i += stride) atomicAdd(&cnt[row[i]], 1);
}

// exclusive scan, 1024 elements/block (256 thr x 4), partial per block + block sums
__global__ __launch_bounds__(256) void scan1_k(const int* __restrict__ in, int* __restrict__ out,
                                               int* __restrict__ bsums, int n) {
    __shared__ int lds[256];
    int t = threadIdx.x;
    int base = blockIdx.x * 1024 + t * 4;
    int v0 = (base + 0 < n) ? in[base + 0] : 0;
    int v1 = (base + 1 < n) ? in[base + 1] : 0;
    int v2 = (base + 2 < n) ? in[base + 2] : 0;
    int v3 = (base + 3 < n) ? in[base + 3] : 0;
    lds[t] = v0 + v1 + v2 + v3;
    __syncthreads();
    for (int off = 1; off < 256; off <<= 1) {
        int x = (t >= off) ? lds[t - off] : 0;
        __syncthreads();
        lds[t] += x;
        __syncthreads();
    }
    if (t == 255) bsums[blockIdx.x] = lds[255];
    int run = (t == 0) ? 0 : lds[t - 1];
    if (base + 0 < n) out[base + 0] = run; run += v0;
    if (base + 1 < n) out[base + 1] = run; run += v1;
    if (base + 2 < n) out[base + 2] = run; run += v2;
    if (base + 3 < n) out[base + 3] = run;
}

__global__ void scan2_k(int* bsums, int nb) {  // nb <= 256, single block
    __shared__ int lds[256];
    int t = threadIdx.x;
    int v = (t < nb) ? bsums[t] : 0;
    lds[t] = v;
    __syncthreads();
    for (int off = 1; off < 256; off <<= 1) {
        int x = (t >= off) ? lds[t - off] : 0;
        __syncthreads();
        lds[t] += x;
        __syncthreads();
    }
    if (t < nb) bsums[t] = (t == 0) ? 0 : lds[t - 1];
}

__global__ __launch_bounds__(256) void scan3_k(int* __restrict__ out, const int* __restrict__ bsums, int n) {
    int add = bsums[blockIdx.x];
    int base = blockIdx.x * 1024 + threadIdx.x * 4;
#pragma unroll
    for (int j = 0; j < 4; j++)
        if (base + j < n) out[base + j] += add;
}

__global__ __launch_bounds__(256) void scatter_k(const int* __restrict__ row, const int* __restrict__ col,
                                                 const float* __restrict__ val, const int* __restrict__ off,
                                                 int* __restrict__ cursor, int2* __restrict__ csr, int n) {
    int i = blockIdx.x * blockDim.x + threadIdx.x;
    int stride = gridDim.x * blockDim.x;
    for (; i < n; i += stride) {
        int r = row[i];
        int pos = off[r] + atomicAdd(&cursor[r], 1);
        csr[pos] = make_int2(col[i], __float_as_int(val[i]));
    }
}

// ---------------- SpMM gather, fp16 z-table ----------------
// 16 lanes per output row; each lane covers 4 dims (uint2 = 4 halves = 8B,
// 16 lanes x 8B = 128B coalesced per gathered z-row). fp32 accumulate.
// Optional fp32 and/or fp16 outputs.

__device__ __forceinline__ void fma_h4(float4& acc, float v, uint2 r) {
    __half2 a = *(__half2*)&r.x;
    __half2 b = *(__half2*)&r.y;
    float2 fa = __half22float2(a);
    float2 fb = __half22float2(b);
    acc.x = fmaf(v, fa.x, acc.x);
    acc.y = fmaf(v, fa.y, acc.y);
    acc.z = fmaf(v, fb.x, acc.z);
    acc.w = fmaf(v, fb.y, acc.w);
}

__global__ __launch_bounds__(256) void spmm_k(const int2* __restrict__ csr, const int* __restrict__ off,
                                              const int* __restrict__ cnt, const uint2* __restrict__ z,
                                              float4* __restrict__ out32, uint2* __restrict__ out16,
                                              int nrows) {
    int g = blockIdx.x * 16 + (threadIdx.x >> 4);
    int l = threadIdx.x & 15;
    if (g >= nrows) return;
    int start = off[g], deg = cnt[g];
    float4 acc = make_float4(0.f, 0.f, 0.f, 0.f);
    for (int j = 0; j < deg; j += 4) {
        int j1 = min(j + 1, deg - 1);
        int j2 = min(j + 2, deg - 1);
        int j3 = min(j + 3, deg - 1);
        int2 e0 = csr[start + j];
        int2 e1 = csr[start + j1];
        int2 e2 = csr[start + j2];
        int2 e3 = csr[start + j3];
        uint2 r0 = z[(size_t)e0.x * 16 + l];
        uint2 r1 = z[(size_t)e1.x * 16 + l];
        uint2 r2 = z[(size_t)e2.x * 16 + l];
        uint2 r3 = z[(size_t)e3.x * 16 + l];
        float v0 = __int_as_float(e0.y);
        float v1 = (j + 1 < deg) ? __int_as_float(e1.y) : 0.f;
        float v2 = (j + 2 < deg) ? __int_as_float(e2.y) : 0.f;
        float v3 = (j + 3 < deg) ? __int_as_float(e3.y) : 0.f;
        fma_h4(acc, v0, r0);
        fma_h4(acc, v1, r1);
        fma_h4(acc, v2, r2);
        fma_h4(acc, v3, r3);
    }
    if (out32) out32[(size_t)g * 16 + l] = acc;
    if (out16) {
        __half2 p0 = __floats2half2_rn(acc.x, acc.y);
        __half2 p1 = __floats2half2_rn(acc.z, acc.w);
        uint2 o;
        o.x = *(unsigned*)&p0;
        o.y = *(unsigned*)&p1;
        out16[(size_t)g * 16 + l] = o;
    }
}

// ---------------- dense projection: z16 = fp16(x @ W), D=64 ----------------
// block = 256 threads computes 256 rows x 64 cols; K-tile 32 staged in LDS
// (x transposed 32KB + W 8KB = 40KB -> 4 blocks/CU); 8x8 per-thread register tile.

template <int K>
__global__ __launch_bounds__(256) void gemm64_k(const float* __restrict__ x, const float* __restrict__ w,
                                                __half* __restrict__ z16, int nrows) {
    __shared__ float xs[32][256];  // [kk][row_local]
    __shared__ float wsh[32][64];  // [kk][col]
    int t = threadIdx.x;
    int tx = t & 7;    // col group: cols tx*8 .. tx*8+7
    int ty = t >> 3;   // row group: rows ty*8 .. ty*8+7
    int r0 = blockIdx.x * 256;

    float acc[8][8];
#pragma unroll
    for (int i = 0; i < 8; i++)
#pragma unroll
        for (int j = 0; j < 8; j++) acc[i][j] = 0.f;

    for (int k0 = 0; k0 < K; k0 += 32) {
        __syncthreads();  // previous tile fully consumed
        // stage x tile: this thread owns global row r0+t, k in [k0, k0+32)
        {
            int row = r0 + t;
            float4 f[8];
            if (row < nrows) {
                const float* xp = x + (size_t)row * K + k0;
#pragma unroll
                for (int q = 0; q < 8; q++) f[q] = *(const float4*)&xp[q * 4];
            } else {
#pragma unroll
                for (int q = 0; q < 8; q++) f[q] = make_float4(0.f, 0.f, 0.f, 0.f);
            }
#pragma unroll
            for (int q = 0; q < 8; q++) {
                xs[q * 4 + 0][t] = f[q].x;
                xs[q * 4 + 1][t] = f[q].y;
                xs[q * 4 + 2][t] = f[q].z;
                xs[q * 4 + 3][t] = f[q].w;
            }
            // stage W tile: 32x64 contiguous floats, 8 per thread
            const float* wp = w + (size_t)k0 * 64;
            float* wflat = &wsh[0][0];
            *(float4*)&wflat[t * 8 + 0] = *(const float4*)&wp[t * 8 + 0];
            *(float4*)&wflat[t * 8 + 4] = *(const float4*)&wp[t * 8 + 4];
        }
        __syncthreads();
#pragma unroll 8
        for (int kk = 0; kk < 32; kk++) {
            float a[8], b[8];
            *(float4*)&a[0] = *(float4*)&xs[kk][ty * 8 + 0];
            *(float4*)&a[4] = *(float4*)&xs[kk][ty * 8 + 4];
            *(float4*)&b[0] = *(float4*)&wsh[kk][tx * 8 + 0];
            *(float4*)&b[4] = *(float4*)&wsh[kk][tx * 8 + 4];
#pragma unroll
            for (int i = 0; i < 8; i++)
#pragma unroll
                for (int j = 0; j < 8; j++) acc[i][j] = fmaf(a[i], b[j], acc[i][j]);
        }
    }

    int row0 = r0 + ty * 8;
    if (row0 < nrows) {  // nrows % 8 == 0, so all 8 rows valid together
#pragma unroll
        for (int i = 0; i < 8; i++) {
            __half2 p0 = __floats2half2_rn(acc[i][0], acc[i][1]);
            __half2 p1 = __floats2half2_rn(acc[i][2], acc[i][3]);
            __half2 p2 = __floats2half2_rn(acc[i][4], acc[i][5]);
            __half2 p3 = __floats2half2_rn(acc[i][6], acc[i][7]);
            uint4 o;
            o.x = *(unsigned*)&p0;
            o.y = *(unsigned*)&p1;
            o.z = *(unsigned*)&p2;
            o.w = *(unsigned*)&p3;
            *(uint4*)&z16[(size_t)(row0 + i) * 64 + tx * 8] = o;
        }
    }
}

// ---------------- launch ----------------

extern "C" void kernel_launch(void* const* d_in, const int* in_sizes, int n_in,
                              void* d_out, int out_size, void* d_ws, size_t ws_size,
                              hipStream_t stream) {
    const float* x_paper  = (const float*)d_in[0];
    const float* x_author = (const float*)d_in[1];
    const float* W_paper  = (const float*)d_in[2];
    const float* W_author = (const float*)d_in[3];
    const int*   pa_row   = (const int*)d_in[4];
    const int*   pa_col   = (const int*)d_in[5];
    const float* pa_val   = (const float*)d_in[6];
    const int*   ap_row   = (const int*)d_in[7];
    const int*   ap_col   = (const int*)d_in[8];
    const float* ap_val   = (const float*)d_in[9];

    char* ws = (char*)d_ws;
    size_t o = 0;
    auto alloc = [&](size_t bytes) -> char* {
        char* p = ws + o;
        o += (bytes + 255) & ~(size_t)255;
        return p;
    };
    __half* zp16  = (__half*)alloc((size_t)NP * 64 * 2);  // also reused for g
    __half* za16  = (__half*)alloc((size_t)NA * 64 * 2);
    __half* h16   = (__half*)alloc((size_t)NA * 64 * 2);  // h and h2
    __half* pap16 = (__half*)alloc((size_t)NP * 64 * 2);
    int2*  csr_pa = (int2*)alloc((size_t)NE * 8);
    int2*  csr_ap = (int2*)alloc((size_t)NE * 8);
    int* cnt_pa = (int*)alloc(NA * 4);
    int* off_pa = (int*)alloc(NA * 4);
    int* cnt_ap = (int*)alloc(NP * 4);
    int* off_ap = (int*)alloc(NP * 4);
    int* cursor = (int*)alloc(NP * 4);
    int* bsums  = (int*)alloc(1024 * 4);

    float* out_pap   = (float*)d_out;
    float* out_papap = out_pap + (size_t)NP * 64;
    float* out_apa   = out_papap + (size_t)NP * 64;

    const int nb_a = (NA + 1023) / 1024;  // 98
    const int nb_p = (NP + 1023) / 1024;  // 196

    // CSR build: pa (rows = authors), ap (rows = papers)
    hipMemsetAsync(cnt_pa, 0, NA * 4, stream);
    hipMemsetAsync(cnt_ap, 0, NP * 4, stream);
    hist_k<<<1024, 256, 0, stream>>>(pa_row, cnt_pa, NE);
    hist_k<<<1024, 256, 0, stream>>>(ap_row, cnt_ap, NE);

    scan1_k<<<nb_a, 256, 0, stream>>>(cnt_pa, off_pa, bsums, NA);
    scan2_k<<<1, 256, 0, stream>>>(bsums, nb_a);
    scan3_k<<<nb_a, 256, 0, stream>>>(off_pa, bsums, NA);
    hipMemsetAsync(cursor, 0, NA * 4, stream);
    scatter_k<<<1024, 256, 0, stream>>>(pa_row, pa_col, pa_val, off_pa, cursor, csr_pa, NE);

    scan1_k<<<nb_p, 256, 0, stream>>>(cnt_ap, off_ap, bsums, NP);
    scan2_k<<<1, 256, 0, stream>>>(bsums, nb_p);
    scan3_k<<<nb_p, 256, 0, stream>>>(off_ap, bsums, NP);
    hipMemsetAsync(cursor, 0, NP * 4, stream);
    scatter_k<<<1024, 256, 0, stream>>>(ap_row, ap_col, ap_val, off_ap, cursor, csr_ap, NE);

    // projections (register-tiled GEMM, fp16 output)
    gemm64_k<256><<<(NP + 255) / 256, 256, 0, stream>>>(x_paper, W_paper, zp16, NP);
    gemm64_k<128><<<(NA + 255) / 256, 256, 0, stream>>>(x_author, W_author, za16, NA);

    // P-A-P: h = pa@zp (fp16) ; pap = ap@h (fp32 out + fp16 copy)
    spmm_k<<<NA / 16, 256, 0, stream>>>(csr_pa, off_pa, cnt_pa, (const uint2*)zp16,
                                        nullptr, (uint2*)h16, NA);
    spmm_k<<<NP / 16, 256, 0, stream>>>(csr_ap, off_ap, cnt_ap, (const uint2*)h16,
                                        (float4*)out_pap, (uint2*)pap16, NP);
    // P-A-P-A-P: h2 = pa@pap (fp16, reuse h16) ; papap = ap@h2 (fp32)
    spmm_k<<<NA / 16, 256, 0, stream>>>(csr_pa, off_pa, cnt_pa, (const uint2*)pap16,
                                        nullptr, (uint2*)h16, NA);
    spmm_k<<<NP / 16, 256, 0, stream>>>(csr_ap, off_ap, cnt_ap, (const uint2*)h16,
                                        (float4*)out_papap, nullptr, NP);
    // A-P-A: g = ap@za (fp16, reuse zp16 buffer) ; apa = pa@g (fp32)
    spmm_k<<<NP / 16, 256, 0, stream>>>(csr_ap, off_ap, cnt_ap, (const uint2*)za16,
                                        nullptr, (uint2*)zp16, NP);
    spmm_k<<<NA / 16, 256, 0, stream>>>(csr_pa, off_pa, cnt_pa, (const uint2*)zp16,
                                        (float4*)out_apa, nullptr, NA);
}